// Round 7
// baseline (423.903 us; speedup 1.0000x reference)
//
#include <hip/hip_runtime.h>
#include <stdint.h>

typedef unsigned long long u64;
typedef __attribute__((ext_vector_type(8))) short short8;   // 8 bf16 (4 VGPRs)
typedef __attribute__((ext_vector_type(4))) float f32x4;

#define KROWS  262144
#define DDIM   64
#define NQ     1024
#define NC     256                // K-chunks
#define CHUNK  (KROWS / NC)       // 1024 rows
#define SUB    128                // rows per LDS subtile
#define NSUB   (CHUNK / SUB)      // 8
#define KC_PER 4                  // u32 keys kept per (chunk,query) = one uint4
#define BIAS   128.0f             // acc bias => sims positive => raw bits monotone
#define SIMMASK 0xFFFFFC00u       // top 22 bits sim, low 10 bits row-in-chunk

#define WSK_BYTES   ((size_t)NQ * NC * KC_PER * 4)          // 4 MB
#define MB_BYTES    ((size_t)KROWS * DDIM * 2)              // 32 MB bf16 image

__device__ __forceinline__ uint32_t ord32(float f) {
    uint32_t u = __float_as_uint(f);
    return (u & 0x80000000u) ? ~u : (u | 0x80000000u);
}
__device__ __forceinline__ uint32_t maxu(uint32_t a, uint32_t b) { return a > b ? a : b; }
__device__ __forceinline__ uint32_t minu(uint32_t a, uint32_t b) { return a < b ? a : b; }
// sorted-desc pair fold: 3 VALU
__device__ __forceinline__ void fold2(uint32_t& t0, uint32_t& t1, uint32_t k) {
    t1 = maxu(t1, minu(t0, k));
    t0 = maxu(t0, k);
}
// sorted-desc 4-list fold: 7 VALU
__device__ __forceinline__ void fold4(uint32_t (&t)[4], uint32_t k) {
    uint32_t n1 = maxu(t[1], minu(t[0], k));
    uint32_t n2 = maxu(t[2], minu(t[1], k));
    uint32_t n3 = maxu(t[3], minu(t[2], k));
    t[0] = maxu(t[0], k);
    t[1] = n1; t[2] = n2; t[3] = n3;
}
// HW packed fp32->bf16 (RNE)
__device__ __forceinline__ uint32_t cvtpk(float a, float b) {
    uint32_t r;
    asm("v_cvt_pk_bf16_f32 %0, %1, %2" : "=v"(r) : "v"(a), "v"(b));
    return r;   // lo = bf16(a), hi = bf16(b)
}
// async global->LDS DMA, 16B per lane; LDS dest is wave-uniform base +
// lane*16 (linear) — required by HW.
__device__ __forceinline__ void gl_lds16(const uint16_t* g, uint16_t* l) {
    __builtin_amdgcn_global_load_lds(
        (const __attribute__((address_space(1))) void*)g,
        (__attribute__((address_space(3))) void*)l, 16, 0, 0);
}

// Pre-pass (R4-proven): Mf (fp32) -> Mb (bf16) in the exact tiled+swizzled
// LDS image p1 stages. Subtile st = R>>7; slot s = row*8 + c_lds (row =
// R&127) holds global 16B-chunk cg = c_lds ^ (row&7) of row R. p1's DMA
// source is then fully linear; compute reads use the same swizzle.
__global__ __launch_bounds__(256) void pc(const float* __restrict__ Mf,
                                          uint16_t* __restrict__ Mb) {
    const int g = blockIdx.x * 256 + threadIdx.x;       // 16B-slot id
    const int row = (g >> 3) & 127;
    const int cl  = g & 7;
    const int cg  = cl ^ (row & 7);
    const size_t R = ((size_t)(g >> 10)) * 128 + (size_t)row;
    const float* src = Mf + R * DDIM + cg * 8;
    const float4 f0 = ((const float4*)src)[0];
    const float4 f1 = ((const float4*)src)[1];
    uint4 wv;
    wv.x = cvtpk(f0.x, f0.y); wv.y = cvtpk(f0.z, f0.w);
    wv.z = cvtpk(f1.x, f1.y); wv.w = cvtpk(f1.z, f1.w);
    *(uint4*)(Mb + (size_t)g * 8) = wv;
}

// Kernel 1 (R14): EXACT R4 compute structure (32q/wave, 64 VGPR — the only
// register budget this allocator honors without spilling; R3/R6 both proved
// 80+ live regs => spill) with the sync upgraded to a counted-vmcnt depth-2
// DMA pipeline (T3/T4): 3 LDS buffers, prologue issues pairs(0,1); each
// iter waits vmcnt(2) (retires ONLY the pair issued two compute phases ago;
// R4's __syncthreads drained vmcnt(0), exposing the just-issued pair's
// latency at all 8 barriers), raw s_barrier, issue pair(sb+2), compute(sb).
// Safety: buf[(sb+2)%3] overwrite is barrier-protected (compute(sb-1) done
// by all waves; its ds_reads are consumed by pre-barrier MFMAs so lgkmcnt
// drains naturally); full unroll => %3 indices compile-time; sched_barrier
// pins the phase boundaries (rule #18).
__global__ __launch_bounds__(512)
__attribute__((amdgpu_waves_per_eu(4, 8)))
void p1pre(const float* __restrict__ Qg,
           const uint16_t* __restrict__ Mb,
           uint32_t* __restrict__ wsK) {
    __shared__ __align__(16) uint16_t stage[3 * 8192];   // 3 x 16 KiB
    const int t = threadIdx.x;
    const int lane = t & 63;
    const int w = t >> 6;
    const int quad = lane >> 4;
    const int m = lane & 15;
    const int qcol = blockIdx.x;        // 0..3
    const int chunk = blockIdx.y;
    const int qBase = qcol * 256 + w * 32;

    // A-frags: A[m=lane&15][k=quad*8+j], fp32->bf16 via HW cvt. [qt][khalf]
    short8 afr[2][2];
    #pragma unroll
    for (int qt = 0; qt < 2; ++qt)
        #pragma unroll
        for (int kh = 0; kh < 2; ++kh) {
            const float* qp = Qg + (size_t)(qBase + qt * 16 + m) * DDIM + quad * 8 + kh * 32;
            const float4 f0 = ((const float4*)qp)[0];
            const float4 f1 = ((const float4*)qp)[1];
            union { short8 s; uint32_t u[4]; } cv;
            cv.u[0] = cvtpk(f0.x, f0.y);
            cv.u[1] = cvtpk(f0.z, f0.w);
            cv.u[2] = cvtpk(f1.x, f1.y);
            cv.u[3] = cvtpk(f1.z, f1.w);
            afr[qt][kh] = cv.s;
        }
    const f32x4 bias = {BIAS, BIAS, BIAS, BIAS};

    // 8 lists (query class = qt*4+reg), sorted top-2 pairs; row class = m
    uint32_t tA[8], tB[8];   // tA >= tB
    #pragma unroll
    for (int li = 0; li < 8; ++li) { tA[li] = 0u; tB[li] = 0u; }

    // DMA staging: subtile (chunk*8+sb) is 8192 consecutive uint16 in Mb.
    const uint16_t* mbBase = Mb + ((size_t)chunk * 8) * 8192;
    auto stage_sub = [&](int sb, int buf) {
        const uint16_t* s0 = mbBase + (size_t)sb * 8192;
        uint16_t* d0 = stage + buf * 8192;
        gl_lds16(s0 + (size_t)t * 8,         d0 + (size_t)t * 8);
        gl_lds16(s0 + (size_t)(t + 512) * 8, d0 + (size_t)(t + 512) * 8);
    };

    stage_sub(0, 0);          // depth-2 prologue: pairs (0) and (1) in flight
    stage_sub(1, 1);
    #pragma unroll
    for (int sb = 0; sb < NSUB; ++sb) {
        // retire the OLDEST DMA pair only (pair sb, issued 2 phases ago);
        // pair sb+1 stays in flight across the barrier (T4: never drain to 0
        // mid-loop). Last iter: only pair 7 outstanding -> must drain fully.
        if (sb == NSUB - 1) asm volatile("s_waitcnt vmcnt(0)" ::: "memory");
        else                asm volatile("s_waitcnt vmcnt(2)" ::: "memory");
        __builtin_amdgcn_s_barrier();
        __builtin_amdgcn_sched_barrier(0);          // pin phase boundary
        if (sb + 2 < NSUB) stage_sub(sb + 2, (sb + 2) % 3);  // issue-early
        const uint16_t* bufp = stage + (sb % 3) * 8192;
        const uint32_t pb = (uint32_t)m + (uint32_t)sb * 128u;   // row10 base
        #pragma unroll
        for (int rt = 0; rt < 8; ++rt) {
            const int r = rt * 16 + m;   // lane's row-in-subtile (B col n)
            const short8 v0 = *(const short8*)(bufp + r * 64 + ((quad       ^ (m & 7)) * 8));
            const short8 v1 = *(const short8*)(bufp + r * 64 + (((quad + 4) ^ (m & 7)) * 8));
            f32x4 c0, c1;
            c0 = __builtin_amdgcn_mfma_f32_16x16x32_bf16(afr[0][0], v0, bias, 0, 0, 0);
            c0 = __builtin_amdgcn_mfma_f32_16x16x32_bf16(afr[0][1], v1, c0,   0, 0, 0);
            c1 = __builtin_amdgcn_mfma_f32_16x16x32_bf16(afr[1][0], v0, bias, 0, 0, 0);
            c1 = __builtin_amdgcn_mfma_f32_16x16x32_bf16(afr[1][1], v1, c1,   0, 0, 0);
            const uint32_t posm = pb + (uint32_t)(rt * 16);   // row10, <1024
            #pragma unroll
            for (int reg = 0; reg < 4; ++reg) {
                fold2(tA[reg],     tB[reg],     (__float_as_uint(c0[reg]) & SIMMASK) | posm);
                fold2(tA[4 + reg], tB[4 + reg], (__float_as_uint(c1[reg]) & SIMMASK) | posm);
            }
        }
    }

    // merge 16 row-classes per query: butterfly xor 1,2,4,8 across m lanes.
    #pragma unroll
    for (int g = 0; g < 2; ++g) {
        uint32_t fl[4][4];
        #pragma unroll
        for (int r4 = 0; r4 < 4; ++r4) {
            fl[r4][0] = tA[g * 4 + r4]; fl[r4][1] = tB[g * 4 + r4];
            fl[r4][2] = 0u;             fl[r4][3] = 0u;
        }
        #pragma unroll
        for (int d = 1; d <= 8; d <<= 1) {
            const int nv = (d == 1) ? 2 : 4;   // remote valid count
            #pragma unroll
            for (int r4 = 0; r4 < 4; ++r4) {
                uint32_t rm[4];
                #pragma unroll
                for (int s = 0; s < 4; ++s)
                    if (s < nv) rm[s] = __shfl_xor(fl[r4][s], d, 64);
                #pragma unroll
                for (int s = 0; s < 4; ++s)
                    if (s < nv) fold4(fl[r4], rm[s]);
            }
        }
        if (m == 0) {   // lanes 0,16,32,48 hold merged lists for this group
            #pragma unroll
            for (int r4 = 0; r4 < 4; ++r4) {
                const int q = qBase + g * 16 + quad * 4 + r4;
                uint4 v4; v4.x = fl[r4][0]; v4.y = fl[r4][1];
                v4.z = fl[r4][2]; v4.w = fl[r4][3];
                // wsK is [q][chunk] so p2 reads coalesce
                *(uint4*)(wsK + ((size_t)q * NC + (size_t)chunk) * KC_PER) = v4;
            }
        }
    }
}

// Fallback (ws too small for Mb): the proven R1 fused-staging kernel, 32q.
__global__ __launch_bounds__(512)
__attribute__((amdgpu_waves_per_eu(4, 8)))
void p1lds(const float* __restrict__ Qg,
           const float* __restrict__ Mf,
           uint32_t* __restrict__ wsK) {
    __shared__ __align__(16) uint16_t stage[2 * 8192];   // 2 x 16 KiB dbuf
    const int t = threadIdx.x;
    const int lane = t & 63;
    const int w = t >> 6;
    const int quad = lane >> 4;
    const int m = lane & 15;
    const int qcol = blockIdx.x;
    const int chunk = blockIdx.y;
    const int qBase = qcol * 256 + w * 32;
    const int rowChunk = chunk * CHUNK;

    short8 afr[2][2];
    #pragma unroll
    for (int qt = 0; qt < 2; ++qt)
        #pragma unroll
        for (int kh = 0; kh < 2; ++kh) {
            const float* qp = Qg + (size_t)(qBase + qt * 16 + m) * DDIM + quad * 8 + kh * 32;
            const float4 f0 = ((const float4*)qp)[0];
            const float4 f1 = ((const float4*)qp)[1];
            union { short8 s; uint32_t u[4]; } cv;
            cv.u[0] = cvtpk(f0.x, f0.y);
            cv.u[1] = cvtpk(f0.z, f0.w);
            cv.u[2] = cvtpk(f1.x, f1.y);
            cv.u[3] = cvtpk(f1.z, f1.w);
            afr[qt][kh] = cv.s;
        }
    const f32x4 bias = {BIAS, BIAS, BIAS, BIAS};

    uint32_t tA[8], tB[8];
    #pragma unroll
    for (int li = 0; li < 8; ++li) { tA[li] = 0u; tB[li] = 0u; }

    const int sr0 = t >> 3;
    const int sc0 = (t & 7) ^ (sr0 & 7);
    auto stage_sub = [&](int sb, int buf) {
        const float* base = Mf + (size_t)(rowChunk + sb * SUB + sr0) * DDIM + sc0 * 8;
        const float4 a0 = ((const float4*)base)[0];
        const float4 a1 = ((const float4*)base)[1];
        const float4 b0 = ((const float4*)(base + 64 * DDIM))[0];
        const float4 b1 = ((const float4*)(base + 64 * DDIM))[1];
        uint16_t* bp = stage + buf * 8192;
        uint4 w0, w1;
        w0.x = cvtpk(a0.x, a0.y); w0.y = cvtpk(a0.z, a0.w);
        w0.z = cvtpk(a1.x, a1.y); w0.w = cvtpk(a1.z, a1.w);
        w1.x = cvtpk(b0.x, b0.y); w1.y = cvtpk(b0.z, b0.w);
        w1.z = cvtpk(b1.x, b1.y); w1.w = cvtpk(b1.z, b1.w);
        *(uint4*)(bp + (size_t)t * 8) = w0;
        *(uint4*)(bp + (size_t)(t + 512) * 8) = w1;
    };

    stage_sub(0, 0);
    #pragma unroll 2
    for (int sb = 0; sb < NSUB; ++sb) {
        __syncthreads();
        if (sb + 1 < NSUB) stage_sub(sb + 1, (sb + 1) & 1);
        const uint16_t* bufp = stage + (sb & 1) * 8192;
        const uint32_t pb = (uint32_t)m + (uint32_t)sb * 128u;
        #pragma unroll
        for (int rt = 0; rt < 8; ++rt) {
            const int r = rt * 16 + m;
            const short8 v0 = *(const short8*)(bufp + r * 64 + ((quad       ^ (m & 7)) * 8));
            const short8 v1 = *(const short8*)(bufp + r * 64 + (((quad + 4) ^ (m & 7)) * 8));
            f32x4 c0, c1;
            c0 = __builtin_amdgcn_mfma_f32_16x16x32_bf16(afr[0][0], v0, bias, 0, 0, 0);
            c0 = __builtin_amdgcn_mfma_f32_16x16x32_bf16(afr[0][1], v1, c0,   0, 0, 0);
            c1 = __builtin_amdgcn_mfma_f32_16x16x32_bf16(afr[1][0], v0, bias, 0, 0, 0);
            c1 = __builtin_amdgcn_mfma_f32_16x16x32_bf16(afr[1][1], v1, c1,   0, 0, 0);
            const uint32_t posm = pb + (uint32_t)(rt * 16);
            #pragma unroll
            for (int reg = 0; reg < 4; ++reg) {
                fold2(tA[reg],     tB[reg],     (__float_as_uint(c0[reg]) & SIMMASK) | posm);
                fold2(tA[4 + reg], tB[4 + reg], (__float_as_uint(c1[reg]) & SIMMASK) | posm);
            }
        }
    }

    #pragma unroll
    for (int g = 0; g < 2; ++g) {
        uint32_t fl[4][4];
        #pragma unroll
        for (int r4 = 0; r4 < 4; ++r4) {
            fl[r4][0] = tA[g * 4 + r4]; fl[r4][1] = tB[g * 4 + r4];
            fl[r4][2] = 0u;             fl[r4][3] = 0u;
        }
        #pragma unroll
        for (int d = 1; d <= 8; d <<= 1) {
            const int nv = (d == 1) ? 2 : 4;
            #pragma unroll
            for (int r4 = 0; r4 < 4; ++r4) {
                uint32_t rm[4];
                #pragma unroll
                for (int s = 0; s < 4; ++s)
                    if (s < nv) rm[s] = __shfl_xor(fl[r4][s], d, 64);
                #pragma unroll
                for (int s = 0; s < 4; ++s)
                    if (s < nv) fold4(fl[r4], rm[s]);
            }
        }
        if (m == 0) {
            #pragma unroll
            for (int r4 = 0; r4 < 4; ++r4) {
                const int q = qBase + g * 16 + quad * 4 + r4;
                uint4 v4; v4.x = fl[r4][0]; v4.y = fl[r4][1];
                v4.z = fl[r4][2]; v4.w = fl[r4][3];
                *(uint4*)(wsK + ((size_t)q * NC + (size_t)chunk) * KC_PER) = v4;
            }
        }
    }
}

// Kernel 2: one block (4 waves) per query; wsK [q][chunk] => each wave's 64
// uint4 loads are 1 KB contiguous. Per-wave bitonic top-16 of 64 chunks ->
// 64 candidates -> exact fp32 rescore (16/wave) -> wave 0 top-5 -> gather.
__global__ __launch_bounds__(256) void p2(const float* __restrict__ Qg,
                                          const float* __restrict__ Mf,
                                          const uint32_t* __restrict__ wsK,
                                          float* __restrict__ out) {
    __shared__ uint32_t candRow[64];
    __shared__ u64 candScore[64];
    const int Q = blockIdx.x;
    const int t = threadIdx.x;
    const int lane = t & 63;
    const int w = t >> 6;               // 0..3

    // 1. load this lane's chunk keys (sorted desc), stamp provenance
    const int c = w * 64 + lane;
    const uint4 k4 = *(const uint4*)(wsK + ((size_t)Q * NC + (size_t)c) * KC_PER);
    uint32_t s[16];
    s[0] = (k4.x & SIMMASK) | ((uint32_t)lane << 2) | 0u;
    s[1] = (k4.y & SIMMASK) | ((uint32_t)lane << 2) | 1u;
    s[2] = (k4.z & SIMMASK) | ((uint32_t)lane << 2) | 2u;
    s[3] = (k4.w & SIMMASK) | ((uint32_t)lane << 2) | 3u;
    #pragma unroll
    for (int i = 4; i < 16; ++i) s[i] = 0u;

    // 2. butterfly merge: after all 6 stages every lane holds the wave's
    //    top-16 sorted desc.
    #pragma unroll
    for (int d = 1; d <= 32; d <<= 1) {
        uint32_t r[16];
        #pragma unroll
        for (int i = 0; i < 16; ++i) r[i] = __shfl_xor(s[i], d, 64);
        uint32_t mm[16];
        #pragma unroll
        for (int i = 0; i < 16; ++i) mm[i] = maxu(s[i], r[15 - i]);  // bitonic split
        #pragma unroll
        for (int dd = 8; dd >= 1; dd >>= 1) {       // bitonic merge -> desc
            #pragma unroll
            for (int i = 0; i < 16; ++i) {
                if ((i & dd) == 0) {
                    const uint32_t hi = maxu(mm[i], mm[i + dd]);
                    const uint32_t lo = minu(mm[i], mm[i + dd]);
                    mm[i] = hi; mm[i + dd] = lo;
                }
            }
        }
        #pragma unroll
        for (int i = 0; i < 16; ++i) s[i] = mm[i];
    }

    // 3. lanes 0..15 resolve candidate lane's key -> global row
    uint32_t ck = s[0];
    #pragma unroll
    for (int j = 1; j < 16; ++j) ck = (lane == j) ? s[j] : ck;
    if (lane < 16) {
        const int srcLane = (int)((ck >> 2) & 63u);
        const int jj = (int)(ck & 3u);
        const int c2 = w * 64 + srcLane;
        const uint32_t raw = wsK[((size_t)Q * NC + (size_t)c2) * KC_PER + jj];
        candRow[w * 16 + lane] = (uint32_t)c2 * (uint32_t)CHUNK + (raw & 1023u);
    }
    __syncthreads();

    // 4. exact fp32 rescore: wave w handles candidates w*16 .. w*16+15
    const float qv = Qg[(size_t)Q * DDIM + lane];
    #pragma unroll
    for (int j = 0; j < 16; ++j) {
        const uint32_t grow = candRow[w * 16 + j];
        const float v = Mf[(size_t)grow * DDIM + lane];
        float p = qv * v;
        #pragma unroll
        for (int off = 32; off >= 1; off >>= 1) p += __shfl_xor(p, off, 64);
        if (lane == 0)
            candScore[w * 16 + j] = ((u64)ord32(p) << 32) | (u64)(~grow);
    }
    __syncthreads();

    // 5. wave 0: top-5 of 64 (lane <-> candidate), gather output rows
    if (w == 0) {
        u64 key = candScore[lane];
        #pragma unroll
        for (int it = 0; it < 5; ++it) {
            u64 best = key;
            #pragma unroll
            for (int off = 32; off >= 1; off >>= 1) {
                const u64 o = __shfl_xor(best, off, 64);
                best = o > best ? o : best;
            }
            const uint32_t wrow = ~(uint32_t)best;   // winner global row
            out[((size_t)Q * 5 + it) * DDIM + lane] = Mf[(size_t)wrow * DDIM + lane];
            key = (key == best) ? 0ull : key;        // distinct rows -> unique
        }
    }
}

extern "C" void kernel_launch(void* const* d_in, const int* in_sizes, int n_in,
                              void* d_out, int out_size, void* d_ws, size_t ws_size,
                              hipStream_t stream) {
    const float* Qg = (const float*)d_in[0];
    const float* Mf = (const float*)d_in[1];
    float* out = (float*)d_out;
    uint32_t* wsK = (uint32_t*)d_ws;                       // 4 MB, [q][chunk][4]

    if (ws_size >= WSK_BYTES + MB_BYTES) {
        uint16_t* Mb = (uint16_t*)((char*)d_ws + WSK_BYTES);  // 32 MB bf16 image
        pc<<<(KROWS * DDIM / 8) / 256, 256, 0, stream>>>(Mf, Mb);
        p1pre<<<dim3(4, NC), 512, 0, stream>>>(Qg, Mb, wsK);
    } else {
        p1lds<<<dim3(4, NC), 512, 0, stream>>>(Qg, Mf, wsK);
    }
    p2<<<NQ, 256, 0, stream>>>(Qg, Mf, wsK, out);
}

// Round 8
// 167.430 us; speedup vs baseline: 2.5318x; 2.5318x over previous
//
#include <hip/hip_runtime.h>
#include <stdint.h>

typedef unsigned long long u64;
typedef __attribute__((ext_vector_type(8))) short short8;   // 8 bf16 (4 VGPRs)
typedef __attribute__((ext_vector_type(4))) float f32x4;

#define KROWS  262144
#define DDIM   64
#define NQ     1024
#define NC     256                // K-chunks
#define CHUNK  (KROWS / NC)       // 1024 rows
#define SUB    128                // rows per LDS subtile
#define NSUB   (CHUNK / SUB)      // 8
#define KC_PER 4                  // u32 keys kept per (chunk,query) = one uint4
#define BIAS   128.0f             // acc bias => sims positive => raw bits monotone
#define SIMMASK 0xFFFFFC00u       // top 22 bits sim, low 10 bits row-in-chunk

__device__ __forceinline__ uint32_t ord32(float f) {
    uint32_t u = __float_as_uint(f);
    return (u & 0x80000000u) ? ~u : (u | 0x80000000u);
}
__device__ __forceinline__ uint32_t maxu(uint32_t a, uint32_t b) { return a > b ? a : b; }
__device__ __forceinline__ uint32_t minu(uint32_t a, uint32_t b) { return a < b ? a : b; }

// R15: sorted-desc pair fold in 2 VALU (was 3). Under the invariant t0>=t1:
//   max(t1, min(t0,k)) == median(t0,t1,k)   [case check: k>=t0 -> t0;
//   t0>k>=t1 -> k; k<t1 -> t1 — all equal med3]. The compiler CANNOT derive
// this (only valid given sortedness), so v_med3_u32 is hand-asm.
__device__ __forceinline__ void fold2(uint32_t& t0, uint32_t& t1, uint32_t k) {
    uint32_t med;
    asm("v_med3_u32 %0, %1, %2, %3" : "=v"(med) : "v"(t0), "v"(t1), "v"(k));
    t0 = maxu(t0, k);
    t1 = med;
}
// sorted-desc 4-list fold: 4 VALU (was 7), same med3 lemma per adjacent pair.
__device__ __forceinline__ void fold4(uint32_t (&t)[4], uint32_t k) {
    uint32_t n1, n2, n3;
    asm("v_med3_u32 %0, %1, %2, %3" : "=v"(n1) : "v"(t[0]), "v"(t[1]), "v"(k));
    asm("v_med3_u32 %0, %1, %2, %3" : "=v"(n2) : "v"(t[1]), "v"(t[2]), "v"(k));
    asm("v_med3_u32 %0, %1, %2, %3" : "=v"(n3) : "v"(t[2]), "v"(t[3]), "v"(k));
    t[0] = maxu(t[0], k);
    t[1] = n1; t[2] = n2; t[3] = n3;
}
// HW packed fp32->bf16 (RNE)
__device__ __forceinline__ uint32_t cvtpk(float a, float b) {
    uint32_t r;
    asm("v_cvt_pk_bf16_f32 %0, %1, %2" : "=v"(r) : "v"(a), "v"(b));
    return r;   // lo = bf16(a), hi = bf16(b)
}

// Kernel 1 (R15): the R1-proven fused-staging kernel (85.1 us benched;
// 64 VGPR, no spill) + med3 fold opts. Consolidation rationale: the ledger
// over 8 rounds shows F = dur - p1 - pc = 89.6 us in EVERY non-spilled
// config, so R1 (85.1+F) == R4 (19.5+68.9+F) within noise; all five
// structural p1 variants (256-thr, T14-reg, global-direct, 64q, counted
// vmcnt) spilled or regressed — this allocator spills rather than re-tier
// above ~64 live VGPRs (proven R3/R6/R7). The only safe lever left in p1
// is op count: fold2 3->2, fold4 7->4, bit-identical results.
__global__ __launch_bounds__(512)
__attribute__((amdgpu_waves_per_eu(4, 8)))
void p1(const float* __restrict__ Qg,
        const float* __restrict__ Mf,
        uint32_t* __restrict__ wsK) {
    __shared__ __align__(16) uint16_t stage[2 * 8192];   // 2 x 16 KiB dbuf
    const int t = threadIdx.x;
    const int lane = t & 63;
    const int w = t >> 6;
    const int quad = lane >> 4;
    const int m = lane & 15;
    const int qcol = blockIdx.x;
    const int chunk = blockIdx.y;
    const int qBase = qcol * 256 + w * 32;
    const int rowChunk = chunk * CHUNK;

    // A-frags: A[m=lane&15][k=quad*8+j], fp32->bf16 via HW cvt. [qt][khalf]
    short8 afr[2][2];
    #pragma unroll
    for (int qt = 0; qt < 2; ++qt)
        #pragma unroll
        for (int kh = 0; kh < 2; ++kh) {
            const float* qp = Qg + (size_t)(qBase + qt * 16 + m) * DDIM + quad * 8 + kh * 32;
            const float4 f0 = ((const float4*)qp)[0];
            const float4 f1 = ((const float4*)qp)[1];
            union { short8 s; uint32_t u[4]; } cv;
            cv.u[0] = cvtpk(f0.x, f0.y);
            cv.u[1] = cvtpk(f0.z, f0.w);
            cv.u[2] = cvtpk(f1.x, f1.y);
            cv.u[3] = cvtpk(f1.z, f1.w);
            afr[qt][kh] = cv.s;
        }
    const f32x4 bias = {BIAS, BIAS, BIAS, BIAS};

    // 8 lists (query class = qt*4+reg), sorted top-2 pairs; row class = m
    uint32_t tA[8], tB[8];   // tA >= tB
    #pragma unroll
    for (int li = 0; li < 8; ++li) { tA[li] = 0u; tB[li] = 0u; }

    // staging: thread t owns 16B-slots t and t+512 of the 1024-slot subtile.
    // LDS slot (row=s>>3, c=s&7) holds global 16B-chunk (c ^ (row&7)) of that
    // row (swizzle => compute reads are 2-way max conflict).
    const int sr0 = t >> 3;
    const int sc0 = (t & 7) ^ (sr0 & 7);     // (t+512)>>3 = sr0+64, same &7
    auto stage_sub = [&](int sb, int buf) {
        const float* base = Mf + (size_t)(rowChunk + sb * SUB + sr0) * DDIM + sc0 * 8;
        const float4 a0 = ((const float4*)base)[0];
        const float4 a1 = ((const float4*)base)[1];
        const float4 b0 = ((const float4*)(base + 64 * DDIM))[0];
        const float4 b1 = ((const float4*)(base + 64 * DDIM))[1];
        uint16_t* bp = stage + buf * 8192;
        uint4 w0, w1;
        w0.x = cvtpk(a0.x, a0.y); w0.y = cvtpk(a0.z, a0.w);
        w0.z = cvtpk(a1.x, a1.y); w0.w = cvtpk(a1.z, a1.w);
        w1.x = cvtpk(b0.x, b0.y); w1.y = cvtpk(b0.z, b0.w);
        w1.z = cvtpk(b1.x, b1.y); w1.w = cvtpk(b1.z, b1.w);
        *(uint4*)(bp + (size_t)t * 8) = w0;
        *(uint4*)(bp + (size_t)(t + 512) * 8) = w1;
    };

    stage_sub(0, 0);
    #pragma unroll 2
    for (int sb = 0; sb < NSUB; ++sb) {
        __syncthreads();   // staging of sb (prev iter) visible to all waves
        if (sb + 1 < NSUB) stage_sub(sb + 1, (sb + 1) & 1);  // other buffer: safe
        const uint16_t* bufp = stage + (sb & 1) * 8192;
        const uint32_t pb = (uint32_t)m + (uint32_t)sb * 128u;   // row10 base
        #pragma unroll
        for (int rt = 0; rt < 8; ++rt) {
            const int r = rt * 16 + m;   // lane's row-in-subtile (B col n)
            const short8 v0 = *(const short8*)(bufp + r * 64 + ((quad       ^ (m & 7)) * 8));
            const short8 v1 = *(const short8*)(bufp + r * 64 + (((quad + 4) ^ (m & 7)) * 8));
            f32x4 c0, c1;
            c0 = __builtin_amdgcn_mfma_f32_16x16x32_bf16(afr[0][0], v0, bias, 0, 0, 0);
            c0 = __builtin_amdgcn_mfma_f32_16x16x32_bf16(afr[0][1], v1, c0,   0, 0, 0);
            c1 = __builtin_amdgcn_mfma_f32_16x16x32_bf16(afr[1][0], v0, bias, 0, 0, 0);
            c1 = __builtin_amdgcn_mfma_f32_16x16x32_bf16(afr[1][1], v1, c1,   0, 0, 0);
            const uint32_t posm = pb + (uint32_t)(rt * 16);   // (pos<<4)|m, <1024
            #pragma unroll
            for (int reg = 0; reg < 4; ++reg) {
                fold2(tA[reg],     tB[reg],     (__float_as_uint(c0[reg]) & SIMMASK) | posm);
                fold2(tA[4 + reg], tB[4 + reg], (__float_as_uint(c1[reg]) & SIMMASK) | posm);
            }
        }
    }

    // merge 16 row-classes per query: butterfly xor 1,2,4,8 across m lanes.
    #pragma unroll
    for (int g = 0; g < 2; ++g) {
        uint32_t fl[4][4];
        #pragma unroll
        for (int r4 = 0; r4 < 4; ++r4) {
            fl[r4][0] = tA[g * 4 + r4]; fl[r4][1] = tB[g * 4 + r4];
            fl[r4][2] = 0u;             fl[r4][3] = 0u;
        }
        #pragma unroll
        for (int d = 1; d <= 8; d <<= 1) {
            const int nv = (d == 1) ? 2 : 4;   // remote valid count
            #pragma unroll
            for (int r4 = 0; r4 < 4; ++r4) {
                uint32_t rm[4];
                #pragma unroll
                for (int s = 0; s < 4; ++s)
                    if (s < nv) rm[s] = __shfl_xor(fl[r4][s], d, 64);
                #pragma unroll
                for (int s = 0; s < 4; ++s)
                    if (s < nv) fold4(fl[r4], rm[s]);
            }
        }
        if (m == 0) {   // lanes 0,16,32,48 hold merged lists for this group
            #pragma unroll
            for (int r4 = 0; r4 < 4; ++r4) {
                const int q = qBase + g * 16 + quad * 4 + r4;
                uint4 v4; v4.x = fl[r4][0]; v4.y = fl[r4][1];
                v4.z = fl[r4][2]; v4.w = fl[r4][3];
                // wsK is [q][chunk] so p2 reads coalesce
                *(uint4*)(wsK + ((size_t)q * NC + (size_t)chunk) * KC_PER) = v4;
            }
        }
    }
}

// Kernel 2: one block (4 waves) per query; wsK [q][chunk] => each wave's 64
// uint4 loads are 1 KB contiguous. Per-wave bitonic top-16 of 64 chunks ->
// 64 candidates -> exact fp32 rescore (16/wave) -> wave 0 top-5 -> gather.
// (Passed R2-R7; bounded <68.6 us by R4's top-5 cutoff. Unchanged.)
__global__ __launch_bounds__(256) void p2(const float* __restrict__ Qg,
                                          const float* __restrict__ Mf,
                                          const uint32_t* __restrict__ wsK,
                                          float* __restrict__ out) {
    __shared__ uint32_t candRow[64];
    __shared__ u64 candScore[64];
    const int Q = blockIdx.x;
    const int t = threadIdx.x;
    const int lane = t & 63;
    const int w = t >> 6;               // 0..3

    // 1. load this lane's chunk keys (sorted desc), stamp provenance
    const int c = w * 64 + lane;
    const uint4 k4 = *(const uint4*)(wsK + ((size_t)Q * NC + (size_t)c) * KC_PER);
    uint32_t s[16];
    s[0] = (k4.x & SIMMASK) | ((uint32_t)lane << 2) | 0u;
    s[1] = (k4.y & SIMMASK) | ((uint32_t)lane << 2) | 1u;
    s[2] = (k4.z & SIMMASK) | ((uint32_t)lane << 2) | 2u;
    s[3] = (k4.w & SIMMASK) | ((uint32_t)lane << 2) | 3u;
    #pragma unroll
    for (int i = 4; i < 16; ++i) s[i] = 0u;

    // 2. butterfly merge: after all 6 stages every lane holds the wave's
    //    top-16 sorted desc.
    #pragma unroll
    for (int d = 1; d <= 32; d <<= 1) {
        uint32_t r[16];
        #pragma unroll
        for (int i = 0; i < 16; ++i) r[i] = __shfl_xor(s[i], d, 64);
        uint32_t mm[16];
        #pragma unroll
        for (int i = 0; i < 16; ++i) mm[i] = maxu(s[i], r[15 - i]);  // bitonic split
        #pragma unroll
        for (int dd = 8; dd >= 1; dd >>= 1) {       // bitonic merge -> desc
            #pragma unroll
            for (int i = 0; i < 16; ++i) {
                if ((i & dd) == 0) {
                    const uint32_t hi = maxu(mm[i], mm[i + dd]);
                    const uint32_t lo = minu(mm[i], mm[i + dd]);
                    mm[i] = hi; mm[i + dd] = lo;
                }
            }
        }
        #pragma unroll
        for (int i = 0; i < 16; ++i) s[i] = mm[i];
    }

    // 3. lanes 0..15 resolve candidate lane's key -> global row
    uint32_t ck = s[0];
    #pragma unroll
    for (int j = 1; j < 16; ++j) ck = (lane == j) ? s[j] : ck;
    if (lane < 16) {
        const int srcLane = (int)((ck >> 2) & 63u);
        const int jj = (int)(ck & 3u);
        const int c2 = w * 64 + srcLane;
        const uint32_t raw = wsK[((size_t)Q * NC + (size_t)c2) * KC_PER + jj];
        candRow[w * 16 + lane] = (uint32_t)c2 * (uint32_t)CHUNK + (raw & 1023u);
    }
    __syncthreads();

    // 4. exact fp32 rescore: wave w handles candidates w*16 .. w*16+15
    const float qv = Qg[(size_t)Q * DDIM + lane];
    #pragma unroll
    for (int j = 0; j < 16; ++j) {
        const uint32_t grow = candRow[w * 16 + j];
        const float v = Mf[(size_t)grow * DDIM + lane];
        float p = qv * v;
        #pragma unroll
        for (int off = 32; off >= 1; off >>= 1) p += __shfl_xor(p, off, 64);
        if (lane == 0)
            candScore[w * 16 + j] = ((u64)ord32(p) << 32) | (u64)(~grow);
    }
    __syncthreads();

    // 5. wave 0: top-5 of 64 (lane <-> candidate), gather output rows
    if (w == 0) {
        u64 key = candScore[lane];
        #pragma unroll
        for (int it = 0; it < 5; ++it) {
            u64 best = key;
            #pragma unroll
            for (int off = 32; off >= 1; off >>= 1) {
                const u64 o = __shfl_xor(best, off, 64);
                best = o > best ? o : best;
            }
            const uint32_t wrow = ~(uint32_t)best;   // winner global row
            out[((size_t)Q * 5 + it) * DDIM + lane] = Mf[(size_t)wrow * DDIM + lane];
            key = (key == best) ? 0ull : key;        // distinct rows -> unique
        }
    }
}

extern "C" void kernel_launch(void* const* d_in, const int* in_sizes, int n_in,
                              void* d_out, int out_size, void* d_ws, size_t ws_size,
                              hipStream_t stream) {
    const float* Qg = (const float*)d_in[0];
    const float* Mf = (const float*)d_in[1];
    float* out = (float*)d_out;
    uint32_t* wsK = (uint32_t*)d_ws;   // [q][chunk][4] u32 = 4 MB

    p1<<<dim3(4, NC), 512, 0, stream>>>(Qg, Mf, wsK);
    p2<<<NQ, 256, 0, stream>>>(Qg, Mf, wsK, out);
}

// Round 9
// 159.869 us; speedup vs baseline: 2.6516x; 1.0473x over previous
//
#include <hip/hip_runtime.h>
#include <stdint.h>

typedef unsigned long long u64;
typedef __attribute__((ext_vector_type(8))) short short8;   // 8 bf16 (4 VGPRs)
typedef __attribute__((ext_vector_type(4))) float f32x4;

#define KROWS  262144
#define DDIM   64
#define NQ     1024
#define NC     256                // K-chunks
#define CHUNK  (KROWS / NC)       // 1024 rows
#define SUB    256                // rows per LDS subtile (R16: was 128)
#define NSUB   (CHUNK / SUB)      // 4
#define KC_PER 4                  // u32 keys kept per (chunk,query) = one uint4
#define BIAS   128.0f             // acc bias => sims positive => raw bits monotone
#define SIMMASK 0xFFFFFC00u       // top 22 bits sim, low 10 bits row-in-chunk

__device__ __forceinline__ uint32_t ord32(float f) {
    uint32_t u = __float_as_uint(f);
    return (u & 0x80000000u) ? ~u : (u | 0x80000000u);
}
__device__ __forceinline__ uint32_t maxu(uint32_t a, uint32_t b) { return a > b ? a : b; }
__device__ __forceinline__ uint32_t minu(uint32_t a, uint32_t b) { return a < b ? a : b; }

// sorted-desc pair fold in 2 VALU (R15-proven, -7 us). Under t0>=t1:
//   max(t1, min(t0,k)) == median(t0,t1,k). Only valid given sortedness, so
// the compiler cannot derive it — hand v_med3_u32.
__device__ __forceinline__ void fold2(uint32_t& t0, uint32_t& t1, uint32_t k) {
    uint32_t med;
    asm("v_med3_u32 %0, %1, %2, %3" : "=v"(med) : "v"(t0), "v"(t1), "v"(k));
    t0 = maxu(t0, k);
    t1 = med;
}
// sorted-desc 4-list fold: 4 VALU, same med3 lemma per adjacent pair.
__device__ __forceinline__ void fold4(uint32_t (&t)[4], uint32_t k) {
    uint32_t n1, n2, n3;
    asm("v_med3_u32 %0, %1, %2, %3" : "=v"(n1) : "v"(t[0]), "v"(t[1]), "v"(k));
    asm("v_med3_u32 %0, %1, %2, %3" : "=v"(n2) : "v"(t[1]), "v"(t[2]), "v"(k));
    asm("v_med3_u32 %0, %1, %2, %3" : "=v"(n3) : "v"(t[2]), "v"(t[3]), "v"(k));
    t[0] = maxu(t[0], k);
    t[1] = n1; t[2] = n2; t[3] = n3;
}
// HW packed fp32->bf16 (RNE)
__device__ __forceinline__ uint32_t cvtpk(float a, float b) {
    uint32_t r;
    asm("v_cvt_pk_bf16_f32 %0, %1, %2" : "=v"(r) : "v"(a), "v"(b));
    return r;   // lo = bf16(a), hi = bf16(b)
}

// Kernel 1 (R16): R15 kernel with two structural-only changes:
// (1) CHUNK-MAJOR grid dim3(NC,4): the 4 qcol partner blocks of a chunk get
//     ids {c, c+256, c+512, c+768} -> same XCD slot under round-robin, and M
//     (64 MB) fits L3 entirely -> passes 2-4 re-read from L3. R15's
//     qcol-fast grid put partners on 4 DIFFERENT XCDs -> FETCH was 142 MB
//     (2.2x of M). Expect ~70-85 MB.
// (2) SUB=256: 2 x 32 KiB buffers (64 KiB LDS) -> barriers/block 8 -> 4 with
//     2x compute per barrier; 2 blocks/CU resident (160//64) so when one
//     block sits at its barrier drain the other's 8 waves keep the CU fed.
// Staging = two sequential copies of the R1-proven 4-load group (low spill
// risk); per-128-row LDS layout, swizzle, posm encoding bit-identical to
// R15 -> absmax unchanged. 64 VGPR budget untouched (R3/R6/R7: allocator
// spills rather than re-tier above ~64 live regs).
__global__ __launch_bounds__(512)
__attribute__((amdgpu_waves_per_eu(4, 8)))
void p1(const float* __restrict__ Qg,
        const float* __restrict__ Mf,
        uint32_t* __restrict__ wsK) {
    __shared__ __align__(16) uint16_t stage[2 * 16384];   // 2 x 32 KiB dbuf
    const int t = threadIdx.x;
    const int lane = t & 63;
    const int w = t >> 6;
    const int quad = lane >> 4;
    const int m = lane & 15;
    const int chunk = blockIdx.x;       // chunk-major (see header note)
    const int qcol = blockIdx.y;
    const int qBase = qcol * 256 + w * 32;
    const int rowChunk = chunk * CHUNK;

    // A-frags: A[m=lane&15][k=quad*8+j], fp32->bf16 via HW cvt. [qt][khalf]
    short8 afr[2][2];
    #pragma unroll
    for (int qt = 0; qt < 2; ++qt)
        #pragma unroll
        for (int kh = 0; kh < 2; ++kh) {
            const float* qp = Qg + (size_t)(qBase + qt * 16 + m) * DDIM + quad * 8 + kh * 32;
            const float4 f0 = ((const float4*)qp)[0];
            const float4 f1 = ((const float4*)qp)[1];
            union { short8 s; uint32_t u[4]; } cv;
            cv.u[0] = cvtpk(f0.x, f0.y);
            cv.u[1] = cvtpk(f0.z, f0.w);
            cv.u[2] = cvtpk(f1.x, f1.y);
            cv.u[3] = cvtpk(f1.z, f1.w);
            afr[qt][kh] = cv.s;
        }
    const f32x4 bias = {BIAS, BIAS, BIAS, BIAS};

    // 8 lists (query class = qt*4+reg), sorted top-2 pairs; row class = m
    uint32_t tA[8], tB[8];   // tA >= tB
    #pragma unroll
    for (int li = 0; li < 8; ++li) { tA[li] = 0u; tB[li] = 0u; }

    // staging: within each 128-row sub-subtile (8192 uint16), thread t owns
    // 16B-slots t and t+512. Slot (row=s>>3, c=s&7) holds global 16B-chunk
    // (c ^ (row&7)) of that row — same swizzle as R1/R15, compute reads
    // unchanged (<=2-way conflict, free).
    const int sr0 = t >> 3;                  // 0..63; +512 slot -> row+64
    const int sc0 = (t & 7) ^ (sr0 & 7);     // (sr0+64)&7 == sr0&7
    auto stage_sub = [&](int sb, int buf) {
        #pragma unroll
        for (int ss = 0; ss < 2; ++ss) {     // two 128-row groups per subtile
            const float* base = Mf + (size_t)(rowChunk + sb * SUB + ss * 128 + sr0) * DDIM + sc0 * 8;
            const float4 a0 = ((const float4*)base)[0];
            const float4 a1 = ((const float4*)base)[1];
            const float4 b0 = ((const float4*)(base + 64 * DDIM))[0];
            const float4 b1 = ((const float4*)(base + 64 * DDIM))[1];
            uint16_t* bp = stage + buf * 16384 + ss * 8192;
            uint4 w0, w1;
            w0.x = cvtpk(a0.x, a0.y); w0.y = cvtpk(a0.z, a0.w);
            w0.z = cvtpk(a1.x, a1.y); w0.w = cvtpk(a1.z, a1.w);
            w1.x = cvtpk(b0.x, b0.y); w1.y = cvtpk(b0.z, b0.w);
            w1.z = cvtpk(b1.x, b1.y); w1.w = cvtpk(b1.z, b1.w);
            *(uint4*)(bp + (size_t)t * 8) = w0;
            *(uint4*)(bp + (size_t)(t + 512) * 8) = w1;
        }
    };

    stage_sub(0, 0);
    #pragma unroll 2
    for (int sb = 0; sb < NSUB; ++sb) {
        __syncthreads();   // staging of sb (prev iter) visible to all waves
        if (sb + 1 < NSUB) stage_sub(sb + 1, (sb + 1) & 1);  // other buffer: safe
        const uint16_t* bufp = stage + (sb & 1) * 16384;
        const uint32_t pb = (uint32_t)m + (uint32_t)sb * 256u;   // row10 base
        #pragma unroll
        for (int rt = 0; rt < 16; ++rt) {    // 16 row-tiles of 16 (2 groups)
            const int r = (rt & 7) * 16 + m; // row within 128-row group
            const uint16_t* sp = bufp + (rt >> 3) * 8192 + r * 64;
            const short8 v0 = *(const short8*)(sp + ((quad       ^ (m & 7)) * 8));
            const short8 v1 = *(const short8*)(sp + (((quad + 4) ^ (m & 7)) * 8));
            f32x4 c0, c1;
            c0 = __builtin_amdgcn_mfma_f32_16x16x32_bf16(afr[0][0], v0, bias, 0, 0, 0);
            c0 = __builtin_amdgcn_mfma_f32_16x16x32_bf16(afr[0][1], v1, c0,   0, 0, 0);
            c1 = __builtin_amdgcn_mfma_f32_16x16x32_bf16(afr[1][0], v0, bias, 0, 0, 0);
            c1 = __builtin_amdgcn_mfma_f32_16x16x32_bf16(afr[1][1], v1, c1,   0, 0, 0);
            const uint32_t posm = pb + (uint32_t)(rt * 16);   // row-in-chunk, <1024
            #pragma unroll
            for (int reg = 0; reg < 4; ++reg) {
                fold2(tA[reg],     tB[reg],     (__float_as_uint(c0[reg]) & SIMMASK) | posm);
                fold2(tA[4 + reg], tB[4 + reg], (__float_as_uint(c1[reg]) & SIMMASK) | posm);
            }
        }
    }

    // merge 16 row-classes per query: butterfly xor 1,2,4,8 across m lanes.
    #pragma unroll
    for (int g = 0; g < 2; ++g) {
        uint32_t fl[4][4];
        #pragma unroll
        for (int r4 = 0; r4 < 4; ++r4) {
            fl[r4][0] = tA[g * 4 + r4]; fl[r4][1] = tB[g * 4 + r4];
            fl[r4][2] = 0u;             fl[r4][3] = 0u;
        }
        #pragma unroll
        for (int d = 1; d <= 8; d <<= 1) {
            const int nv = (d == 1) ? 2 : 4;   // remote valid count
            #pragma unroll
            for (int r4 = 0; r4 < 4; ++r4) {
                uint32_t rm[4];
                #pragma unroll
                for (int s = 0; s < 4; ++s)
                    if (s < nv) rm[s] = __shfl_xor(fl[r4][s], d, 64);
                #pragma unroll
                for (int s = 0; s < 4; ++s)
                    if (s < nv) fold4(fl[r4], rm[s]);
            }
        }
        if (m == 0) {   // lanes 0,16,32,48 hold merged lists for this group
            #pragma unroll
            for (int r4 = 0; r4 < 4; ++r4) {
                const int q = qBase + g * 16 + quad * 4 + r4;
                uint4 v4; v4.x = fl[r4][0]; v4.y = fl[r4][1];
                v4.z = fl[r4][2]; v4.w = fl[r4][3];
                // wsK is [q][chunk] so p2 reads coalesce
                *(uint4*)(wsK + ((size_t)q * NC + (size_t)chunk) * KC_PER) = v4;
            }
        }
    }
}

// Kernel 2: one block (4 waves) per query; wsK [q][chunk] => each wave's 64
// uint4 loads are 1 KB contiguous. Per-wave bitonic top-16 of 64 chunks ->
// 64 candidates -> exact fp32 rescore (16/wave) -> wave 0 top-5 -> gather.
// (Passed R2-R8. Unchanged.)
__global__ __launch_bounds__(256) void p2(const float* __restrict__ Qg,
                                          const float* __restrict__ Mf,
                                          const uint32_t* __restrict__ wsK,
                                          float* __restrict__ out) {
    __shared__ uint32_t candRow[64];
    __shared__ u64 candScore[64];
    const int Q = blockIdx.x;
    const int t = threadIdx.x;
    const int lane = t & 63;
    const int w = t >> 6;               // 0..3

    // 1. load this lane's chunk keys (sorted desc), stamp provenance
    const int c = w * 64 + lane;
    const uint4 k4 = *(const uint4*)(wsK + ((size_t)Q * NC + (size_t)c) * KC_PER);
    uint32_t s[16];
    s[0] = (k4.x & SIMMASK) | ((uint32_t)lane << 2) | 0u;
    s[1] = (k4.y & SIMMASK) | ((uint32_t)lane << 2) | 1u;
    s[2] = (k4.z & SIMMASK) | ((uint32_t)lane << 2) | 2u;
    s[3] = (k4.w & SIMMASK) | ((uint32_t)lane << 2) | 3u;
    #pragma unroll
    for (int i = 4; i < 16; ++i) s[i] = 0u;

    // 2. butterfly merge: after all 6 stages every lane holds the wave's
    //    top-16 sorted desc.
    #pragma unroll
    for (int d = 1; d <= 32; d <<= 1) {
        uint32_t r[16];
        #pragma unroll
        for (int i = 0; i < 16; ++i) r[i] = __shfl_xor(s[i], d, 64);
        uint32_t mm[16];
        #pragma unroll
        for (int i = 0; i < 16; ++i) mm[i] = maxu(s[i], r[15 - i]);  // bitonic split
        #pragma unroll
        for (int dd = 8; dd >= 1; dd >>= 1) {       // bitonic merge -> desc
            #pragma unroll
            for (int i = 0; i < 16; ++i) {
                if ((i & dd) == 0) {
                    const uint32_t hi = maxu(mm[i], mm[i + dd]);
                    const uint32_t lo = minu(mm[i], mm[i + dd]);
                    mm[i] = hi; mm[i + dd] = lo;
                }
            }
        }
        #pragma unroll
        for (int i = 0; i < 16; ++i) s[i] = mm[i];
    }

    // 3. lanes 0..15 resolve candidate lane's key -> global row
    uint32_t ck = s[0];
    #pragma unroll
    for (int j = 1; j < 16; ++j) ck = (lane == j) ? s[j] : ck;
    if (lane < 16) {
        const int srcLane = (int)((ck >> 2) & 63u);
        const int jj = (int)(ck & 3u);
        const int c2 = w * 64 + srcLane;
        const uint32_t raw = wsK[((size_t)Q * NC + (size_t)c2) * KC_PER + jj];
        candRow[w * 16 + lane] = (uint32_t)c2 * (uint32_t)CHUNK + (raw & 1023u);
    }
    __syncthreads();

    // 4. exact fp32 rescore: wave w handles candidates w*16 .. w*16+15
    const float qv = Qg[(size_t)Q * DDIM + lane];
    #pragma unroll
    for (int j = 0; j < 16; ++j) {
        const uint32_t grow = candRow[w * 16 + j];
        const float v = Mf[(size_t)grow * DDIM + lane];
        float p = qv * v;
        #pragma unroll
        for (int off = 32; off >= 1; off >>= 1) p += __shfl_xor(p, off, 64);
        if (lane == 0)
            candScore[w * 16 + j] = ((u64)ord32(p) << 32) | (u64)(~grow);
    }
    __syncthreads();

    // 5. wave 0: top-5 of 64 (lane <-> candidate), gather output rows
    if (w == 0) {
        u64 key = candScore[lane];
        #pragma unroll
        for (int it = 0; it < 5; ++it) {
            u64 best = key;
            #pragma unroll
            for (int off = 32; off >= 1; off >>= 1) {
                const u64 o = __shfl_xor(best, off, 64);
                best = o > best ? o : best;
            }
            const uint32_t wrow = ~(uint32_t)best;   // winner global row
            out[((size_t)Q * 5 + it) * DDIM + lane] = Mf[(size_t)wrow * DDIM + lane];
            key = (key == best) ? 0ull : key;        // distinct rows -> unique
        }
    }
}

extern "C" void kernel_launch(void* const* d_in, const int* in_sizes, int n_in,
                              void* d_out, int out_size, void* d_ws, size_t ws_size,
                              hipStream_t stream) {
    const float* Qg = (const float*)d_in[0];
    const float* Mf = (const float*)d_in[1];
    float* out = (float*)d_out;
    uint32_t* wsK = (uint32_t*)d_ws;   // [q][chunk][4] u32 = 4 MB

    p1<<<dim3(NC, 4), 512, 0, stream>>>(Qg, Mf, wsK);   // chunk-major (R16)
    p2<<<NQ, 256, 0, stream>>>(Qg, Mf, wsK, out);
}

// Round 10
// 156.373 us; speedup vs baseline: 2.7108x; 1.0224x over previous
//
#include <hip/hip_runtime.h>
#include <stdint.h>

typedef unsigned long long u64;
typedef __attribute__((ext_vector_type(8))) short short8;   // 8 bf16 (4 VGPRs)
typedef __attribute__((ext_vector_type(4))) float f32x4;

#define KROWS  262144
#define DDIM   64
#define NQ     1024
#define NC     256                // K-chunks
#define CHUNK  (KROWS / NC)       // 1024 rows
#define SUB    256                // rows per LDS subtile
#define NSUB   (CHUNK / SUB)      // 4
#define KC_PER 4                  // u32 keys kept per (chunk,query) = one uint4
#define BIAS   128.0f             // acc bias => sims positive => raw bits monotone
#define SIMMASK 0xFFFFFC00u       // top 22 bits sim, low 10 bits row-in-chunk

__device__ __forceinline__ uint32_t ord32(float f) {
    uint32_t u = __float_as_uint(f);
    return (u & 0x80000000u) ? ~u : (u | 0x80000000u);
}
__device__ __forceinline__ uint32_t maxu(uint32_t a, uint32_t b) { return a > b ? a : b; }
__device__ __forceinline__ uint32_t minu(uint32_t a, uint32_t b) { return a < b ? a : b; }

// sorted-desc pair fold in 2 VALU (R15-proven). Under t0>=t1:
//   max(t1, min(t0,k)) == median(t0,t1,k). Only valid given sortedness —
// compiler cannot derive it, hand v_med3_u32.
__device__ __forceinline__ void fold2(uint32_t& t0, uint32_t& t1, uint32_t k) {
    uint32_t med;
    asm("v_med3_u32 %0, %1, %2, %3" : "=v"(med) : "v"(t0), "v"(t1), "v"(k));
    t0 = maxu(t0, k);
    t1 = med;
}
// sorted-desc 4-list fold: 4 VALU, same med3 lemma per adjacent pair.
__device__ __forceinline__ void fold4(uint32_t (&t)[4], uint32_t k) {
    uint32_t n1, n2, n3;
    asm("v_med3_u32 %0, %1, %2, %3" : "=v"(n1) : "v"(t[0]), "v"(t[1]), "v"(k));
    asm("v_med3_u32 %0, %1, %2, %3" : "=v"(n2) : "v"(t[1]), "v"(t[2]), "v"(k));
    asm("v_med3_u32 %0, %1, %2, %3" : "=v"(n3) : "v"(t[2]), "v"(t[3]), "v"(k));
    t[0] = maxu(t[0], k);
    t[1] = n1; t[2] = n2; t[3] = n3;
}
// HW packed fp32->bf16 (RNE)
__device__ __forceinline__ uint32_t cvtpk(float a, float b) {
    uint32_t r;
    asm("v_cvt_pk_bf16_f32 %0, %1, %2" : "=v"(r) : "v"(a), "v"(b));
    return r;   // lo = bf16(a), hi = bf16(b)
}

// Kernel 1 (R17): R16 kernel with TEMPORALLY-ALIGNED XCD partner mapping.
// R16's dim3(NC,4) put the 4 qcol partners of a chunk on the same XCD slot
// but 256 dispatch ids apart (~32 slots apart ON that XCD) -> only partial
// temporal overlap -> FETCH stayed at ~118 MB (1.8x of M's 64 MB).
// New 1-D mapping: x = ((chunkGroup*4 + qcol) << 3) | xcdSlot, with
// chunk = chunkGroup*8 + xcdSlot. Partners differ by exactly 8 in id ->
// same XCD under id%8 round-robin AND within a 32-id dispatch window ->
// co-resident; chunk slice (256 KB) fetched from HBM once, L2-hit 3x.
// Robustness: under a contiguous-chunked XCD mapping ids 8 apart still
// share an XCD -> degrades to R16 behavior, never below it.
// Everything else bit-identical to R16 (SUB=256, med3 folds, 64 KiB LDS).
__global__ __launch_bounds__(512)
__attribute__((amdgpu_waves_per_eu(4, 8)))
void p1(const float* __restrict__ Qg,
        const float* __restrict__ Mf,
        uint32_t* __restrict__ wsK) {
    __shared__ __align__(16) uint16_t stage[2 * 16384];   // 2 x 32 KiB dbuf
    const int t = threadIdx.x;
    const int lane = t & 63;
    const int w = t >> 6;
    const int quad = lane >> 4;
    const int m = lane & 15;
    // R17 partner-aligned decode (see header note)
    const int x = blockIdx.x;
    const int xcdSlot = x & 7;
    const int pos = x >> 3;             // 0..127
    const int qcol = pos & 3;
    const int chunk = (pos >> 2) * 8 + xcdSlot;
    const int qBase = qcol * 256 + w * 32;
    const int rowChunk = chunk * CHUNK;

    // A-frags: A[m=lane&15][k=quad*8+j], fp32->bf16 via HW cvt. [qt][khalf]
    short8 afr[2][2];
    #pragma unroll
    for (int qt = 0; qt < 2; ++qt)
        #pragma unroll
        for (int kh = 0; kh < 2; ++kh) {
            const float* qp = Qg + (size_t)(qBase + qt * 16 + m) * DDIM + quad * 8 + kh * 32;
            const float4 f0 = ((const float4*)qp)[0];
            const float4 f1 = ((const float4*)qp)[1];
            union { short8 s; uint32_t u[4]; } cv;
            cv.u[0] = cvtpk(f0.x, f0.y);
            cv.u[1] = cvtpk(f0.z, f0.w);
            cv.u[2] = cvtpk(f1.x, f1.y);
            cv.u[3] = cvtpk(f1.z, f1.w);
            afr[qt][kh] = cv.s;
        }
    const f32x4 bias = {BIAS, BIAS, BIAS, BIAS};

    // 8 lists (query class = qt*4+reg), sorted top-2 pairs; row class = m
    uint32_t tA[8], tB[8];   // tA >= tB
    #pragma unroll
    for (int li = 0; li < 8; ++li) { tA[li] = 0u; tB[li] = 0u; }

    // staging: within each 128-row group (8192 uint16), thread t owns 16B
    // slots t and t+512. Slot (row=s>>3, c=s&7) holds global 16B-chunk
    // (c ^ (row&7)) of that row — swizzle => compute reads <=2-way (free).
    const int sr0 = t >> 3;                  // 0..63; +512 slot -> row+64
    const int sc0 = (t & 7) ^ (sr0 & 7);     // (sr0+64)&7 == sr0&7
    auto stage_sub = [&](int sb, int buf) {
        #pragma unroll
        for (int ss = 0; ss < 2; ++ss) {     // two 128-row groups per subtile
            const float* base = Mf + (size_t)(rowChunk + sb * SUB + ss * 128 + sr0) * DDIM + sc0 * 8;
            const float4 a0 = ((const float4*)base)[0];
            const float4 a1 = ((const float4*)base)[1];
            const float4 b0 = ((const float4*)(base + 64 * DDIM))[0];
            const float4 b1 = ((const float4*)(base + 64 * DDIM))[1];
            uint16_t* bp = stage + buf * 16384 + ss * 8192;
            uint4 w0, w1;
            w0.x = cvtpk(a0.x, a0.y); w0.y = cvtpk(a0.z, a0.w);
            w0.z = cvtpk(a1.x, a1.y); w0.w = cvtpk(a1.z, a1.w);
            w1.x = cvtpk(b0.x, b0.y); w1.y = cvtpk(b0.z, b0.w);
            w1.z = cvtpk(b1.x, b1.y); w1.w = cvtpk(b1.z, b1.w);
            *(uint4*)(bp + (size_t)t * 8) = w0;
            *(uint4*)(bp + (size_t)(t + 512) * 8) = w1;
        }
    };

    stage_sub(0, 0);
    #pragma unroll 2
    for (int sb = 0; sb < NSUB; ++sb) {
        __syncthreads();   // staging of sb (prev iter) visible to all waves
        if (sb + 1 < NSUB) stage_sub(sb + 1, (sb + 1) & 1);  // other buffer: safe
        const uint16_t* bufp = stage + (sb & 1) * 16384;
        const uint32_t pb = (uint32_t)m + (uint32_t)sb * 256u;   // row10 base
        #pragma unroll
        for (int rt = 0; rt < 16; ++rt) {    // 16 row-tiles of 16 (2 groups)
            const int r = (rt & 7) * 16 + m; // row within 128-row group
            const uint16_t* sp = bufp + (rt >> 3) * 8192 + r * 64;
            const short8 v0 = *(const short8*)(sp + ((quad       ^ (m & 7)) * 8));
            const short8 v1 = *(const short8*)(sp + (((quad + 4) ^ (m & 7)) * 8));
            f32x4 c0, c1;
            c0 = __builtin_amdgcn_mfma_f32_16x16x32_bf16(afr[0][0], v0, bias, 0, 0, 0);
            c0 = __builtin_amdgcn_mfma_f32_16x16x32_bf16(afr[0][1], v1, c0,   0, 0, 0);
            c1 = __builtin_amdgcn_mfma_f32_16x16x32_bf16(afr[1][0], v0, bias, 0, 0, 0);
            c1 = __builtin_amdgcn_mfma_f32_16x16x32_bf16(afr[1][1], v1, c1,   0, 0, 0);
            const uint32_t posm = pb + (uint32_t)(rt * 16);   // row-in-chunk, <1024
            #pragma unroll
            for (int reg = 0; reg < 4; ++reg) {
                fold2(tA[reg],     tB[reg],     (__float_as_uint(c0[reg]) & SIMMASK) | posm);
                fold2(tA[4 + reg], tB[4 + reg], (__float_as_uint(c1[reg]) & SIMMASK) | posm);
            }
        }
    }

    // merge 16 row-classes per query: butterfly xor 1,2,4,8 across m lanes.
    #pragma unroll
    for (int g = 0; g < 2; ++g) {
        uint32_t fl[4][4];
        #pragma unroll
        for (int r4 = 0; r4 < 4; ++r4) {
            fl[r4][0] = tA[g * 4 + r4]; fl[r4][1] = tB[g * 4 + r4];
            fl[r4][2] = 0u;             fl[r4][3] = 0u;
        }
        #pragma unroll
        for (int d = 1; d <= 8; d <<= 1) {
            const int nv = (d == 1) ? 2 : 4;   // remote valid count
            #pragma unroll
            for (int r4 = 0; r4 < 4; ++r4) {
                uint32_t rm[4];
                #pragma unroll
                for (int s = 0; s < 4; ++s)
                    if (s < nv) rm[s] = __shfl_xor(fl[r4][s], d, 64);
                #pragma unroll
                for (int s = 0; s < 4; ++s)
                    if (s < nv) fold4(fl[r4], rm[s]);
            }
        }
        if (m == 0) {   // lanes 0,16,32,48 hold merged lists for this group
            #pragma unroll
            for (int r4 = 0; r4 < 4; ++r4) {
                const int q = qBase + g * 16 + quad * 4 + r4;
                uint4 v4; v4.x = fl[r4][0]; v4.y = fl[r4][1];
                v4.z = fl[r4][2]; v4.w = fl[r4][3];
                // wsK is [q][chunk] so p2 reads coalesce
                *(uint4*)(wsK + ((size_t)q * NC + (size_t)chunk) * KC_PER) = v4;
            }
        }
    }
}

// Kernel 2: one block (4 waves) per query; wsK [q][chunk] => each wave's 64
// uint4 loads are 1 KB contiguous. Per-wave bitonic top-16 of 64 chunks ->
// 64 candidates -> exact fp32 rescore (16/wave) -> wave 0 top-5 -> gather.
// (Passed R2-R9. Unchanged.)
__global__ __launch_bounds__(256) void p2(const float* __restrict__ Qg,
                                          const float* __restrict__ Mf,
                                          const uint32_t* __restrict__ wsK,
                                          float* __restrict__ out) {
    __shared__ uint32_t candRow[64];
    __shared__ u64 candScore[64];
    const int Q = blockIdx.x;
    const int t = threadIdx.x;
    const int lane = t & 63;
    const int w = t >> 6;               // 0..3

    // 1. load this lane's chunk keys (sorted desc), stamp provenance
    const int c = w * 64 + lane;
    const uint4 k4 = *(const uint4*)(wsK + ((size_t)Q * NC + (size_t)c) * KC_PER);
    uint32_t s[16];
    s[0] = (k4.x & SIMMASK) | ((uint32_t)lane << 2) | 0u;
    s[1] = (k4.y & SIMMASK) | ((uint32_t)lane << 2) | 1u;
    s[2] = (k4.z & SIMMASK) | ((uint32_t)lane << 2) | 2u;
    s[3] = (k4.w & SIMMASK) | ((uint32_t)lane << 2) | 3u;
    #pragma unroll
    for (int i = 4; i < 16; ++i) s[i] = 0u;

    // 2. butterfly merge: after all 6 stages every lane holds the wave's
    //    top-16 sorted desc.
    #pragma unroll
    for (int d = 1; d <= 32; d <<= 1) {
        uint32_t r[16];
        #pragma unroll
        for (int i = 0; i < 16; ++i) r[i] = __shfl_xor(s[i], d, 64);
        uint32_t mm[16];
        #pragma unroll
        for (int i = 0; i < 16; ++i) mm[i] = maxu(s[i], r[15 - i]);  // bitonic split
        #pragma unroll
        for (int dd = 8; dd >= 1; dd >>= 1) {       // bitonic merge -> desc
            #pragma unroll
            for (int i = 0; i < 16; ++i) {
                if ((i & dd) == 0) {
                    const uint32_t hi = maxu(mm[i], mm[i + dd]);
                    const uint32_t lo = minu(mm[i], mm[i + dd]);
                    mm[i] = hi; mm[i + dd] = lo;
                }
            }
        }
        #pragma unroll
        for (int i = 0; i < 16; ++i) s[i] = mm[i];
    }

    // 3. lanes 0..15 resolve candidate lane's key -> global row
    uint32_t ck = s[0];
    #pragma unroll
    for (int j = 1; j < 16; ++j) ck = (lane == j) ? s[j] : ck;
    if (lane < 16) {
        const int srcLane = (int)((ck >> 2) & 63u);
        const int jj = (int)(ck & 3u);
        const int c2 = w * 64 + srcLane;
        const uint32_t raw = wsK[((size_t)Q * NC + (size_t)c2) * KC_PER + jj];
        candRow[w * 16 + lane] = (uint32_t)c2 * (uint32_t)CHUNK + (raw & 1023u);
    }
    __syncthreads();

    // 4. exact fp32 rescore: wave w handles candidates w*16 .. w*16+15
    const float qv = Qg[(size_t)Q * DDIM + lane];
    #pragma unroll
    for (int j = 0; j < 16; ++j) {
        const uint32_t grow = candRow[w * 16 + j];
        const float v = Mf[(size_t)grow * DDIM + lane];
        float p = qv * v;
        #pragma unroll
        for (int off = 32; off >= 1; off >>= 1) p += __shfl_xor(p, off, 64);
        if (lane == 0)
            candScore[w * 16 + j] = ((u64)ord32(p) << 32) | (u64)(~grow);
    }
    __syncthreads();

    // 5. wave 0: top-5 of 64 (lane <-> candidate), gather output rows
    if (w == 0) {
        u64 key = candScore[lane];
        #pragma unroll
        for (int it = 0; it < 5; ++it) {
            u64 best = key;
            #pragma unroll
            for (int off = 32; off >= 1; off >>= 1) {
                const u64 o = __shfl_xor(best, off, 64);
                best = o > best ? o : best;
            }
            const uint32_t wrow = ~(uint32_t)best;   // winner global row
            out[((size_t)Q * 5 + it) * DDIM + lane] = Mf[(size_t)wrow * DDIM + lane];
            key = (key == best) ? 0ull : key;        // distinct rows -> unique
        }
    }
}

extern "C" void kernel_launch(void* const* d_in, const int* in_sizes, int n_in,
                              void* d_out, int out_size, void* d_ws, size_t ws_size,
                              hipStream_t stream) {
    const float* Qg = (const float*)d_in[0];
    const float* Mf = (const float*)d_in[1];
    float* out = (float*)d_out;
    uint32_t* wsK = (uint32_t*)d_ws;   // [q][chunk][4] u32 = 4 MB

    p1<<<dim3(NC * 4), 512, 0, stream>>>(Qg, Mf, wsK);   // R17 partner-aligned 1-D grid
    p2<<<NQ, 256, 0, stream>>>(Qg, Mf, wsK, out);
}